// Round 1
// baseline (1276.481 us; speedup 1.0000x reference)
//
#include <hip/hip_runtime.h>

#define SEQ 365
#define BS  2048
#define HS  64
#define IND 32
#define XXC 5

__device__ __forceinline__ float rcp_(float x) { return __builtin_amdgcn_rcpf(x); }
__device__ __forceinline__ float sig_(float x) { return rcp_(1.0f + __expf(-x)); }
__device__ __forceinline__ float tanh_(float x) { return 1.0f - 2.0f * rcp_(1.0f + __expf(2.0f * x)); }
__device__ __forceinline__ float bcast_(float v, int lane) {
    return __int_as_float(__builtin_amdgcn_readlane(__float_as_int(v), lane));
}

// One wave (64 threads) per batch sample. Lane j owns output columns
// (j, 64+j, 128+j). All weights live in VGPRs (loaded once, ~306 regs);
// h is broadcast across lanes each k via v_readlane -> no per-step LDS
// traffic (LDS-staged variants are LDS-pipe-bound at ~600+ us).
__global__ __launch_bounds__(64, 1)
void tlstm_kernel(const float* __restrict__ x_for_h,
                  const float* __restrict__ x_for_x,
                  const float* __restrict__ td_in,
                  const float* __restrict__ Wx,    // [32][192]
                  const float* __restrict__ Wxm,   // [5][128]
                  const float* __restrict__ Wh,    // [64][192]
                  const float* __restrict__ Wt1,   // [64]
                  const float* __restrict__ Wt,    // [128]
                  const float* __restrict__ bias,  // [320]
                  float* __restrict__ out)
{
    const int b = blockIdx.x;
    const int j = threadIdx.x;

    // ---- register-resident weights (persist across all 365 steps) ----
    float wx0[IND], wxc[IND], wxo[IND];
#pragma unroll
    for (int k = 0; k < IND; ++k) {
        wx0[k] = Wx[k * 192 + j];
        wxc[k] = Wx[k * 192 + 64 + j];
        wxo[k] = Wx[k * 192 + 128 + j];
    }
    float wh0[HS], whc[HS], who[HS];
#pragma unroll
    for (int k = 0; k < HS; ++k) {
        wh0[k] = Wh[k * 192 + j];
        whc[k] = Wh[k * 192 + 64 + j];
        who[k] = Wh[k * 192 + 128 + j];
    }
    float wm1[XXC], wm2[XXC];
#pragma unroll
    for (int k = 0; k < XXC; ++k) {
        wm1[k] = Wxm[k * 128 + j];
        wm2[k] = Wxm[k * 128 + 64 + j];
    }
    const float wt1j = fminf(Wt1[j], 0.0f);  // torch clamps max=0 (idempotent)
    const float wtA  = Wt[j];
    const float wtB  = Wt[64 + j];
    const float b0 = bias[j], b1 = bias[64 + j], b2 = bias[128 + j];
    const float b3 = bias[192 + j], b4 = bias[256 + j];

    float h = 0.0f, c = 0.0f;

    const float* xh  = x_for_h + (size_t)b * SEQ * IND;
    const float* xx  = x_for_x + (size_t)b * SEQ * XXC;
    const float* tdp = td_in + (size_t)b * SEQ;
    float* outp = out + (size_t)b * SEQ * HS + j;

    for (int t = 0; t < SEQ; ++t) {
        float acc_i = b0, acc_c = b3, acc_o = b4;

        // x @ Wx (x values are wave-uniform -> scalar loads)
#pragma unroll
        for (int k = 0; k < IND; ++k) {
            const float xv = xh[k];
            acc_i = fmaf(xv, wx0[k], acc_i);
            acc_c = fmaf(xv, wxc[k], acc_c);
            acc_o = fmaf(xv, wxo[k], acc_o);
        }
        // h @ Wh (h_k broadcast via readlane; all 64 lanes active)
#pragma unroll
        for (int k = 0; k < HS; ++k) {
            const float hk = bcast_(h, k);
            acc_i = fmaf(hk, wh0[k], acc_i);
            acc_c = fmaf(hk, whc[k], acc_c);
            acc_o = fmaf(hk, who[k], acc_o);
        }
        // xx @ Wxm
        float am1 = b1, am2 = b2;
#pragma unroll
        for (int k = 0; k < XXC; ++k) {
            const float xv = xx[k];
            am1 = fmaf(xv, wm1[k], am1);
            am2 = fmaf(xv, wm2[k], am2);
        }
        const float td = tdp[t];

        const float i_t  = sig_(acc_i);
        const float t1   = sig_(am1 + tanh_(td * wt1j));
        const float t2   = sig_(am2 + tanh_(td * wtA));
        const float capp = tanh_(acc_c);
        const float it1  = i_t * t1;
        // c_tilde = sigmoid((1-i*t1)*c + i*t1*c_app) = sigmoid(c + it1*(capp-c))
        const float ctl  = sig_(fmaf(it1, capp - c, c));
        // c_new = sigmoid((1-i)*c + i*t2*c_app) = sigmoid(c + i*(t2*capp - c))
        const float cn   = sig_(fmaf(i_t, fmaf(t2, capp, -c), c));
        const float o_t  = sig_(fmaf(td, wtB, acc_o));
        const float hn   = o_t + tanh_(ctl);

        outp[(size_t)t * HS] = hn;  // coalesced: lane j -> element j
        h = hn;
        c = cn;
        xh += IND;
        xx += XXC;
    }

    // finals: out = [hidden_seq | h_T | c_T]
    float* hT = out + (size_t)BS * SEQ * HS;
    hT[(size_t)b * HS + j] = h;
    float* cT = hT + (size_t)BS * HS;
    cT[(size_t)b * HS + j] = c;
}

extern "C" void kernel_launch(void* const* d_in, const int* in_sizes, int n_in,
                              void* d_out, int out_size, void* d_ws, size_t ws_size,
                              hipStream_t stream)
{
    const float* x_for_h = (const float*)d_in[0];
    const float* x_for_x = (const float*)d_in[1];
    const float* TimeDiff = (const float*)d_in[2];
    const float* weights_x = (const float*)d_in[3];
    const float* weights_x_maintained = (const float*)d_in[4];
    const float* weights_h = (const float*)d_in[5];
    const float* weights_t1 = (const float*)d_in[6];
    const float* weights_t = (const float*)d_in[7];
    const float* bias = (const float*)d_in[8];
    float* out = (float*)d_out;

    tlstm_kernel<<<BS, 64, 0, stream>>>(x_for_h, x_for_x, TimeDiff,
                                        weights_x, weights_x_maintained, weights_h,
                                        weights_t1, weights_t, bias, out);
}